// Round 11
// baseline (393.136 us; speedup 1.0000x reference)
//
#include <hip/hip_runtime.h>
#include <hip/hip_cooperative_groups.h>
#include <cmath>
#include <stdint.h>

namespace cg = cooperative_groups;

#define NPTS   86016
#define NB     (1 << 18)     // histogram bins per level (f32 score bits >> 12)
#define K_TOP  1000
#define NOUT   3000
#define NWORDS 47            // ceil(3000/64)
#define NTILE  47
#define CAND_CAP 16384
#define ECAP   8192          // edge capacity (expected E ~ hundreds)
#define FCAP   1024          // tie-flag capacity (expected ~20)

// ---- workspace layout (bytes): cnt MUST follow hist (P0 clears both as one range) ----
#define HIST_OFF   0
#define CNT_OFF    (NB * 3 * 4)                 // 3,145,728
// cnt[0..2]=sure_cnt [3..5]=cand_cnt [6..8]=binB [9..11]=Rneed [12]=edge_cnt [13]=flag_cnt
#define KEYS_OFF   (CNT_OFF + 64)
#define LAB_OFF    (KEYS_OFF + NPTS * 8)
#define SURE_OFF   (LAB_OFF + NPTS * 4)
#define CAND_OFF   (SURE_OFF + 3 * 1024 * 8)
#define SURV_OFF   (CAND_OFF + 3 * CAND_CAP * 8)
#define EDGE_OFF   (SURV_OFF + NOUT * 8 + 64)
#define FLAG_OFF   (EDGE_OFF + ECAP * 4)

// stepwise-f32 sigmoid: CR f32 exp, then IEEE f32 add + div (matches numpy per-op chain)
__device__ __forceinline__ float sig_f32_stepwise(float x) {
    float e = (float)exp(-(double)x);   // correctly-rounded f32 exp(-x)
    return 1.0f / (1.0f + e);           // f32 add (CR), f32 div (CR)
}

__device__ __forceinline__ void locate(int g, int& lv, int& p, int& HW) {
    if (g < 65536)      { lv = 0; p = g;         HW = 65536; }
    else if (g < 81920) { lv = 1; p = g - 65536; HW = 16384; }
    else                { lv = 2; p = g - 81920; HW = 4096;  }
}

__global__ __launch_bounds__(1024) void fcos_fused(
        const float* __restrict__ cls0, const float* __restrict__ cls1,
        const float* __restrict__ cls2,
        const float* __restrict__ ctn0, const float* __restrict__ ctn1,
        const float* __restrict__ ctn2,
        const float* __restrict__ reg0, const float* __restrict__ reg1,
        const float* __restrict__ reg2,
        const float* __restrict__ scales,
        unsigned long long* keys, int* labels, int* hist, int* cnt,
        unsigned long long* sure, unsigned long long* cand,
        unsigned long long* surv, unsigned* edges, unsigned* flags,
        float* out) {
    cg::grid_group grid = cg::this_grid();
    const int tid = threadIdx.x;
    const int bid = blockIdx.x;
    const int gtid = bid * 1024 + tid;
    const int nthr = gridDim.x * 1024;

    __shared__ union {
        struct { int part[1024]; int bins[257]; } thr;             // thresh
        unsigned long long sel[1024];                              // select
        struct { unsigned long long L[3][1024];
                 unsigned long long s[NOUT]; } mrg;                // merge+emit (47.4 KB)
        float edg[128][4];                                         // edge tiles
        struct { unsigned ed[ECAP];
                 unsigned long long sup[NWORDS]; } nm;             // nms (33 KB)
    } sm;
    __shared__ int sh_a, sh_b;

    // ---------------- P0: clear hist + cnt (contiguous) ----------------
    for (int i = gtid; i < 3 * NB + 16; i += nthr) hist[i] = 0;
    grid.sync();

    // ---------------- P1: score (one point per thread) ----------------
    if (gtid < NPTS) {
        int g = gtid, lv, p, HW;
        locate(g, lv, p, HW);
        const float* cls = (lv == 0) ? cls0 : ((lv == 1) ? cls1 : cls2);
        const float* ctn = (lv == 0) ? ctn0 : ((lv == 1) ? ctn1 : ctn2);
        const float* basep = cls + p;
        // linear max scan (m = max, idx = first argmax, v = max over prefix [0,idx))
        float m = -INFINITY, v = -INFINITY; int idx = 0;
        for (int ch = 0; ch < 5; ch++) {
            float x[16];
#pragma unroll
            for (int cc = 0; cc < 16; cc++) x[cc] = basep[(size_t)(ch * 16 + cc) * HW];
#pragma unroll
            for (int cc = 0; cc < 16; cc++)
                if (x[cc] > m) { v = m; m = x[cc]; idx = ch * 16 + cc; }
        }
        // joint = sqrt(sig(cls)*sig(ctn)) is weakly monotone in cls -> max joint = joint(m)
        float sc = sig_f32_stepwise(ctn[p]);
        float sM = sig_f32_stepwise(m);
        float jm = __fsqrt_rn(sM * sc);
        float sV = sig_f32_stepwise(v);
        float jv = __fsqrt_rn(sV * sc);
        if (jv == jm) {                        // earlier-index label tie possible
            int f = atomicAdd(&cnt[13], 1);
            if (f < FCAP) flags[f] = (unsigned)g;
        }
        unsigned int bits = __float_as_uint(jm);
        keys[g] = ((unsigned long long)bits << 32) | (0xFFFFFFFFu - (unsigned)g);
        labels[g] = idx;
        atomicAdd(&hist[lv * NB + (int)(bits >> 12)], 1);
    }
    grid.sync();

    // ---------------- P2: thresh (blocks 0-2) + cleanup (block 3) ----------------
    if (bid < 3) {
        int lv = bid;
        const int* h = hist + lv * NB;
        const int4* h4 = (const int4*)(h + tid * 256);
        int sum = 0;
#pragma unroll 16
        for (int k = 0; k < 64; k++) { int4 q = h4[k]; sum += q.x + q.y + q.z + q.w; }
        sm.thr.part[tid] = sum;
        __syncthreads();
        for (int off = 1; off < 1024; off <<= 1) {
            int vv = sm.thr.part[tid] + ((tid + off < 1024) ? sm.thr.part[tid + off] : 0);
            __syncthreads(); sm.thr.part[tid] = vv; __syncthreads();
        }
        int nxt = (tid < 1023) ? sm.thr.part[tid + 1] : 0;
        if (sm.thr.part[tid] >= K_TOP && nxt < K_TOP) { sh_a = tid; sh_b = nxt; }
        __syncthreads();
        int chunk = sh_a, above = sh_b;
        if (tid < 256) sm.thr.bins[tid] = h[chunk * 256 + tid];
        __syncthreads();
        for (int off = 1; off < 256; off <<= 1) {
            int vv = 0;
            if (tid < 256) vv = sm.thr.bins[tid] + ((tid + off < 256) ? sm.thr.bins[tid + off] : 0);
            __syncthreads(); if (tid < 256) sm.thr.bins[tid] = vv; __syncthreads();
        }
        if (tid < 256) {
            int ge    = above + sm.thr.bins[tid];
            int genxt = above + ((tid < 255) ? sm.thr.bins[tid + 1] : 0);
            if (ge >= K_TOP && genxt < K_TOP) {
                cnt[6 + lv] = chunk * 256 + tid;  // cutoff bin B
                cnt[9 + lv] = K_TOP - genxt;      // R needed from bin B
            }
        }
    } else if (bid == 3) {
        // cleanup: one wave per flagged point, shuffle argmax-reduce (first occurrence = min idx)
        int nf = cnt[13]; if (nf > FCAP) nf = FCAP;
        int wave = tid >> 6, lane = tid & 63;
        for (int f = wave; f < nf; f += 16) {
            int g = (int)flags[f], lv, p, HW;
            locate(g, lv, p, HW);
            const float* cls = (lv == 0) ? cls0 : ((lv == 1) ? cls1 : cls2);
            const float* ctn = (lv == 0) ? ctn0 : ((lv == 1) ? ctn1 : ctn2);
            float sc = sig_f32_stepwise(ctn[p]);
            float bestv = -1.0f; int besti = 127;
            // lane covers classes lane and lane+64
            {
                float s = sig_f32_stepwise(cls[(size_t)lane * HW + p]);
                float sj = __fsqrt_rn(s * sc);
                bestv = sj; besti = lane;
            }
            if (lane < 16) {
                int c2 = lane + 64;
                float s = sig_f32_stepwise(cls[(size_t)c2 * HW + p]);
                float sj = __fsqrt_rn(s * sc);
                if (sj > bestv) { bestv = sj; besti = c2; }   // tie keeps smaller idx
            }
            for (int off = 32; off; off >>= 1) {
                float ov = __shfl_xor(bestv, off, 64);
                int   oi = __shfl_xor(besti, off, 64);
                if (ov > bestv || (ov == bestv && oi < besti)) { bestv = ov; besti = oi; }
            }
            if (lane == 0) labels[g] = besti;
        }
    }
    grid.sync();

    // ---------------- P3: compact ----------------
    if (gtid < NPTS) {
        int g = gtid;
        int lv = (g < 65536) ? 0 : (g < 81920 ? 1 : 2);
        unsigned long long key = keys[g];
        int bin = (int)(key >> 44);
        int B = cnt[6 + lv];
        if (bin > B) {
            int i = atomicAdd(&cnt[0 + lv], 1);
            sure[lv * 1024 + i] = key;
        } else if (bin == B) {
            int i = atomicAdd(&cnt[3 + lv], 1);
            if (i < CAND_CAP) cand[lv * CAND_CAP + i] = key;
        }
    }
    grid.sync();

    // ---------------- P4: select (blocks 0-2): cand sort + full level sort ----------------
    if (bid < 3) {
        int lv = bid;
        unsigned long long* c = cand + lv * CAND_CAP;
        int n = cnt[3 + lv]; if (n > CAND_CAP) n = CAND_CAP;
        int R = cnt[9 + lv];
        int Ca = K_TOP - R;
        int m2 = 1; while (m2 < n) m2 <<= 1;
        for (int t = n + tid; t < m2; t += 1024) c[t] = 0ULL;
        __syncthreads();
        for (int k = 2; k <= m2; k <<= 1)
            for (int j = k >> 1; j > 0; j >>= 1) {
                for (int t = tid; t < m2; t += 1024) {
                    int l = t ^ j;
                    if (l > t) {
                        unsigned long long a = c[t], b = c[l];
                        if (((t & k) == 0) ? (a < b) : (a > b)) { c[t] = b; c[l] = a; }
                    }
                }
                __syncthreads();
            }
        sm.sel[tid] = (tid < Ca) ? sure[lv * 1024 + tid]
                                 : ((tid < K_TOP) ? c[tid - Ca] : 0ULL);
        __syncthreads();
        for (int k = 2; k <= 1024; k <<= 1)
            for (int j = k >> 1; j > 0; j >>= 1) {
                int l = tid ^ j;
                if (l > tid) {
                    unsigned long long a = sm.sel[tid], b = sm.sel[l];
                    if (((tid & k) == 0) ? (a < b) : (a > b)) { sm.sel[tid] = b; sm.sel[l] = a; }
                }
                __syncthreads();
            }
        if (tid < K_TOP) surv[lv * K_TOP + tid] = sm.sel[tid];   // sorted descending
    }
    grid.sync();

    // ---------------- P5: merge by ranking + emit (block 0) ----------------
    if (bid == 0) {
#pragma unroll
        for (int lv = 0; lv < 3; lv++)
            sm.mrg.L[lv][tid] = (tid < K_TOP) ? surv[lv * K_TOP + tid] : 0ULL;
        __syncthreads();
        for (int e = tid; e < NOUT; e += 1024) {
            int a = e / K_TOP, i = e - a * K_TOP;
            unsigned long long key = sm.mrg.L[a][i];
            int rank = i;
#pragma unroll
            for (int b = 0; b < 3; b++) {
                if (b == a) continue;
                int lo = 0, hi = K_TOP;
                while (lo < hi) {
                    int mid = (lo + hi) >> 1;
                    if (sm.mrg.L[b][mid] > key) lo = mid + 1; else hi = mid;
                }
                rank += lo;
            }
            sm.mrg.s[rank] = key;    // keys unique -> bijective
        }
        __syncthreads();
        for (int r = tid; r < NOUT; r += 1024) {
            unsigned long long key = sm.mrg.s[r];
            unsigned int bits = (unsigned)(key >> 32);
            float score = __uint_as_float(bits);
            unsigned int g = 0xFFFFFFFFu - (unsigned)(key & 0xFFFFFFFFULL);
            int lv, p;
            if (g < 65536u)      { lv = 0; p = (int)g; }
            else if (g < 81920u) { lv = 1; p = (int)g - 65536; }
            else                 { lv = 2; p = (int)g - 81920; }
            const float* rp = (lv == 0) ? reg0 : ((lv == 1) ? reg1 : reg2);
            int HW = (lv == 0) ? 65536 : ((lv == 1) ? 16384 : 4096);
            int W = 256 >> lv;
            float strideF = (float)(8 << lv);
            float scale = scales[lv];
            int x = p & (W - 1);
            int y = p >> (8 - lv);
            float r0 = fmaxf(0.0f, rp[0 * HW + p] * scale) * strideF;
            float r1 = fmaxf(0.0f, rp[1 * HW + p] * scale) * strideF;
            float r2 = fmaxf(0.0f, rp[2 * HW + p] * scale) * strideF;
            float r3 = fmaxf(0.0f, rp[3 * HW + p] * scale) * strideF;
            float ax = ((float)x + 0.5f) * strideF;
            float ay = ((float)y + 0.5f) * strideF;
            out[r * 4 + 0] = ax - r0;
            out[r * 4 + 1] = ay - r1;
            out[r * 4 + 2] = ax + r2;
            out[r * 4 + 3] = ay + r3;
            out[12000 + r] = score;
            out[15000 + r] = (float)labels[g];
        }
    }
    grid.sync();

    // ---------------- P6: edge extraction (LDS-tiled upper-tri 64x64 tiles) ----------------
    for (int t = bid; t < NTILE * (NTILE + 1) / 2; t += gridDim.x) {
        int ta = 0, rem = t;
        while (rem >= NTILE - ta) { rem -= NTILE - ta; ta++; }
        int tb = ta + rem;                      // ta <= tb
        __syncthreads();
        if (tid < 64) {
            int gi = ta * 64 + tid;
            if (gi < NOUT) {
                sm.edg[tid][0] = out[gi * 4 + 0]; sm.edg[tid][1] = out[gi * 4 + 1];
                sm.edg[tid][2] = out[gi * 4 + 2]; sm.edg[tid][3] = out[gi * 4 + 3];
            }
        } else if (tid < 128) {
            int gj = tb * 64 + (tid - 64);
            if (gj < NOUT) {
                sm.edg[tid][0] = out[gj * 4 + 0]; sm.edg[tid][1] = out[gj * 4 + 1];
                sm.edg[tid][2] = out[gj * 4 + 2]; sm.edg[tid][3] = out[gj * 4 + 3];
            }
        }
        __syncthreads();
#pragma unroll
        for (int q = 0; q < 4; q++) {
            int idx = q * 1024 + tid;
            int ii = idx >> 6, jj = idx & 63;
            int i = ta * 64 + ii, j = tb * 64 + jj;
            if (i < j && j < NOUT) {
                float x1i = sm.edg[ii][0], y1i = sm.edg[ii][1];
                float x2i = sm.edg[ii][2], y2i = sm.edg[ii][3];
                float x1j = sm.edg[64 + jj][0], y1j = sm.edg[64 + jj][1];
                float x2j = sm.edg[64 + jj][2], y2j = sm.edg[64 + jj][3];
                float ai = (x2i - x1i) * (y2i - y1i);
                float aj = (x2j - x1j) * (y2j - y1j);
                float xx1 = fmaxf(x1i, x1j), yy1 = fmaxf(y1i, y1j);
                float xx2 = fminf(x2i, x2j), yy2 = fminf(y2i, y2j);
                float ww = fmaxf(1e-10f, xx2 - xx1);
                float hh = fmaxf(1e-10f, yy2 - yy1);
                float inter = ww * hh;
                float iou = inter / (((ai + aj) - inter) + 1e-14f);
                if ((double)iou > 0.6) {
                    int e = atomicAdd(&cnt[12], 1);
                    if (e < ECAP) edges[e] = ((unsigned)i << 12) | (unsigned)j;
                }
            }
        }
    }
    grid.sync();

    // ---------------- P7: sparse sequential NMS + keep (block 0) ----------------
    if (bid == 0) {
        int E = cnt[12]; if (E > ECAP) E = ECAP;
        int m2 = 1; while (m2 < E) m2 <<= 1;
        for (int t = tid; t < m2; t += 1024) sm.nm.ed[t] = (t < E) ? edges[t] : 0xFFFFFFFFu;
        __syncthreads();
        for (int k = 2; k <= m2; k <<= 1)
            for (int j = k >> 1; j > 0; j >>= 1) {
                for (int t = tid; t < m2; t += 1024) {
                    int l = t ^ j;
                    if (l > t) {
                        unsigned a = sm.nm.ed[t], b = sm.nm.ed[l];
                        if (((t & k) == 0) ? (a > b) : (a < b)) { sm.nm.ed[t] = b; sm.nm.ed[l] = a; }
                    }
                }
                __syncthreads();
            }
        if (tid < 64) {
            int lane = tid;
            unsigned long long supW = 0ULL;
            int ep = 0;
            for (int c = 0; c < NWORDS; c++) {
                unsigned long long cw = __shfl(supW, c, 64);   // complete: sources < c*64 final
                int hi = (c + 1) * 64;
                while (ep < E) {
                    unsigned k = sm.nm.ed[ep];
                    int i = (int)(k >> 12);
                    if (i >= hi) break;
                    int j = (int)(k & 4095);
                    if (!((cw >> (i & 63)) & 1ULL)) {          // source kept -> suppress target
                        if ((j >> 6) == c) cw |= 1ULL << (j & 63);
                        else if (lane == (j >> 6)) supW |= 1ULL << (j & 63);
                    }
                    ep++;
                }
                if (lane == c) supW = cw;
            }
            if (lane < NWORDS) sm.nm.sup[lane] = supW;
        }
        __syncthreads();
        for (int j = tid; j < NOUT; j += 1024) {
            bool s = (sm.nm.sup[j >> 6] >> (j & 63)) & 1ULL;
            float scv = out[12000 + j];
            out[18000 + j] = (!s && ((double)scv > 0.05)) ? 1.0f : 0.0f;
        }
    }
}

extern "C" void kernel_launch(void* const* d_in, const int* in_sizes, int n_in,
                              void* d_out, int out_size, void* d_ws, size_t ws_size,
                              hipStream_t stream) {
    const float* cls0 = (const float*)d_in[0];
    const float* reg0 = (const float*)d_in[1];
    const float* ctn0 = (const float*)d_in[2];
    const float* cls1 = (const float*)d_in[3];
    const float* reg1 = (const float*)d_in[4];
    const float* ctn1 = (const float*)d_in[5];
    const float* cls2 = (const float*)d_in[6];
    const float* reg2 = (const float*)d_in[7];
    const float* ctn2 = (const float*)d_in[8];
    const float* scales = (const float*)d_in[9];

    char* ws = (char*)d_ws;
    int* hist = (int*)(ws + HIST_OFF);
    int* cnt  = (int*)(ws + CNT_OFF);
    unsigned long long* keys = (unsigned long long*)(ws + KEYS_OFF);
    int* labels = (int*)(ws + LAB_OFF);
    unsigned long long* sure = (unsigned long long*)(ws + SURE_OFF);
    unsigned long long* cand = (unsigned long long*)(ws + CAND_OFF);
    unsigned long long* surv = (unsigned long long*)(ws + SURV_OFF);
    unsigned* edges = (unsigned*)(ws + EDGE_OFF);
    unsigned* flags = (unsigned*)(ws + FLAG_OFF);
    float* out = (float*)d_out;

    void* args[] = { (void*)&cls0, (void*)&cls1, (void*)&cls2,
                     (void*)&ctn0, (void*)&ctn1, (void*)&ctn2,
                     (void*)&reg0, (void*)&reg1, (void*)&reg2,
                     (void*)&scales,
                     (void*)&keys, (void*)&labels, (void*)&hist, (void*)&cnt,
                     (void*)&sure, (void*)&cand, (void*)&surv,
                     (void*)&edges, (void*)&flags, (void*)&out };
    hipLaunchCooperativeKernel((const void*)fcos_fused, dim3(256), dim3(1024),
                               args, 0, stream);
}